// Round 8
// baseline (10.146 us; speedup 1.0000x reference)
//
#include <hip/hip_runtime.h>

// SetConv, single fused kernel (uniform-sigma MFMA fast path).
//
//   G[b,m,c] = sum_n exp2(kcu*(x[b,n]-t[b,m])^2) * y[b,n,c]
//   out[b,m,o] = sum_c G[b,m,c]*W[o,c] + bias[o],  kcu = -0.5*log2e/exp(sigma)^2
//
// Grid: (b, mg) = 8*64 = 512 blocks x 512 threads (8 waves). Block owns a
// 16-m tile; waves split n 8-way (128 n/wave = 4 chunks of 32).
// NO pre-loop barrier: every input (y fragments, x slices, t, sigma) is
// loaded straight from global into registers at kernel entry, so all load
// latencies overlap and each wave proceeds to MFMA independently; the only
// block syncs are around the 8-way LDS reduce.
// A-fragment arg uses the 2-op form u=fma(su,x,nst), arg=-u*u with
// su=sqrt(-kcu), nst=-su*tm; f32->f16 via v_cvt_pkrtz (packed, 1 instr/2 elts).
//
// non-uniform sigma: correct VALU fallback (never taken for this input).
//
// Fragment layouts (gfx950 16x16x32, verified round 3, absmax 0.125):
//   A: lane l -> row m = l&15, k = 4*(l>>4) + (j&3) + 16*(j>>2), j=0..7
//   B: lane l -> col c = l&15, k same mapping
//   D: lane l -> col c = l&15, row m = 4*(l>>4) + reg

#define B_SZ 8
#define N_SZ 1024
#define M_SZ 1024
#define C_SZ 16
#define O_SZ 32
#define LOG2E 1.4426950408889634f

typedef _Float16 f16x8 __attribute__((ext_vector_type(8)));
typedef __fp16   h16x2 __attribute__((ext_vector_type(2)));  // cvt_pkrtz return type
typedef float    f32x4 __attribute__((ext_vector_type(4)));

__global__ __launch_bounds__(512, 4) void setconv_fused(
    const float* __restrict__ x,     // (B, N)
    const float* __restrict__ y,     // (B, N, C)
    const float* __restrict__ t,     // (B, M)
    const float* __restrict__ sigma, // (C)
    const float* __restrict__ W,     // (O, C)
    const float* __restrict__ bias,  // (O)
    float* __restrict__ out)         // (B, M, O)
{
    const int tid  = threadIdx.x;
    const int w    = tid >> 6;   // wave 0..7 = n-eighth
    const int lane = tid & 63;
    const int b    = blockIdx.x >> 6;
    const int mg   = blockIdx.x & 63;

    const int g  = lane >> 4;
    const int g4 = 4 * g;
    const int c  = lane & 15;

    __shared__ float red[8][16][16];    // 8 KB: [wave][m][c]

    // ================= hoisted, unconditional global loads =================
    // (1) y B-fragments in fragment order: lane l -> col c, rows per quarter
    const float* ybc = y + ((size_t)b * N_SZ + w * 128) * C_SZ + c;
    float yraw[32];
#pragma unroll
    for (int kc = 0; kc < 4; ++kc) {
#pragma unroll
        for (int jj = 0; jj < 4; ++jj) {
            yraw[kc * 8 + jj]     = ybc[(kc * 32 + g4 + jj) * C_SZ];
            yraw[kc * 8 + 4 + jj] = ybc[(kc * 32 + 16 + g4 + jj) * C_SZ];
        }
    }
    // (2) x slices for this lane's k positions (broadcast across the 16
    //     lanes sharing g; dwordx4 each)
    const float* xw = x + b * N_SZ + w * 128;
    f32x4 xlo[4], xhi[4];
#pragma unroll
    for (int kc = 0; kc < 4; ++kc) {
        xlo[kc] = *(const f32x4*)(xw + kc * 32 + g4);
        xhi[kc] = *(const f32x4*)(xw + kc * 32 + 16 + g4);
    }
    // (3) t value for this lane's m-column
    const float tm = t[b * M_SZ + mg * 16 + c];
    // (4) sigma
    f32x4 s0 = *(const f32x4*)(sigma + 0);
    f32x4 s1 = *(const f32x4*)(sigma + 4);
    f32x4 s2 = *(const f32x4*)(sigma + 8);
    f32x4 s3 = *(const f32x4*)(sigma + 12);

    // work in the load shadow: uni check + y f16 conversion
    const bool uni =
        (s0[0]==s0[1]) && (s0[0]==s0[2]) && (s0[0]==s0[3]) &&
        (s0[0]==s1[0]) && (s0[0]==s1[1]) && (s0[0]==s1[2]) && (s0[0]==s1[3]) &&
        (s0[0]==s2[0]) && (s0[0]==s2[1]) && (s0[0]==s2[2]) && (s0[0]==s2[3]) &&
        (s0[0]==s3[0]) && (s0[0]==s3[1]) && (s0[0]==s3[2]) && (s0[0]==s3[3]);

    f16x8 bf[4];
#pragma unroll
    for (int kc = 0; kc < 4; ++kc)
#pragma unroll
        for (int j = 0; j < 8; ++j)
            bf[kc][j] = (_Float16)yraw[kc * 8 + j];

    if (uni) {
        const float kcu = -0.5f * LOG2E * __builtin_amdgcn_exp2f(-2.0f * LOG2E * s0[0]);
        const float su  = __builtin_sqrtf(-kcu);   // kcu < 0
        const float nst = -su * tm;

        f32x4 acc = {0.f, 0.f, 0.f, 0.f};

#pragma unroll
        for (int kc = 0; kc < 4; ++kc) {
            float e[8];
#pragma unroll
            for (int j = 0; j < 4; ++j) {
                const float u = fmaf(su, xlo[kc][j], nst);
                e[j] = __builtin_amdgcn_exp2f(-u * u);
            }
#pragma unroll
            for (int j = 0; j < 4; ++j) {
                const float u = fmaf(su, xhi[kc][j], nst);
                e[4 + j] = __builtin_amdgcn_exp2f(-u * u);
            }
            union { h16x2 p2[4]; f16x8 v8; } au;
            au.p2[0] = __builtin_amdgcn_cvt_pkrtz(e[0], e[1]);
            au.p2[1] = __builtin_amdgcn_cvt_pkrtz(e[2], e[3]);
            au.p2[2] = __builtin_amdgcn_cvt_pkrtz(e[4], e[5]);
            au.p2[3] = __builtin_amdgcn_cvt_pkrtz(e[6], e[7]);
            acc = __builtin_amdgcn_mfma_f32_16x16x32_f16(au.v8, bf[kc], acc, 0, 0, 0);
        }

        // D: lane -> col c = lane&15, row m = g*4 + r
#pragma unroll
        for (int r = 0; r < 4; ++r)
            red[w][g * 4 + r][c] = acc[r];
        __syncthreads();

        // step 1: reduce over waves (256 threads: (mi, c))
        if (tid < 256) {
            const int mi = tid >> 4, cc = tid & 15;
            float s = red[0][mi][cc];
#pragma unroll
            for (int wv = 1; wv < 8; ++wv) s += red[wv][mi][cc];
            red[0][mi][cc] = s;   // own slot, no cross-thread hazard
        }
        __syncthreads();

        // step 2: 16->32 linear, 512 threads = 512 outputs
        {
            const int mi = tid >> 5, o = tid & 31;
            const float* gr = &red[0][mi][0];
            const float* wr = W + o * C_SZ;
            float v = bias[o];
#pragma unroll
            for (int cc = 0; cc < C_SZ; ++cc) v = fmaf(gr[cc], wr[cc], v);
            out[((size_t)(b * M_SZ + mg * 16 + mi)) * O_SZ + o] = v;
        }
    } else {
        // -------- fallback: arbitrary per-channel sigma (VALU path) --------
        const int j  = lane >> 2;  // 16 n per iter
        const int cg = lane & 3;   // 4 channels
        f32x4 slv = *(const f32x4*)(sigma + cg * 4);
        f32x4 kl;
#pragma unroll
        for (int cc = 0; cc < 4; ++cc)
            kl[cc] = -0.5f * LOG2E * __builtin_amdgcn_exp2f(-2.0f * LOG2E * slv[cc]);

        // wave w owns m = mg*16 + w*2 + {0,1}
        const float tv0 = t[b * M_SZ + mg * 16 + w * 2 + 0];
        const float tv1 = t[b * M_SZ + mg * 16 + w * 2 + 1];

        f32x4 acc0 = {0.f, 0.f, 0.f, 0.f};
        f32x4 acc1 = {0.f, 0.f, 0.f, 0.f};

        for (int it = 0; it < 64; ++it) {
            const int n = it * 16 + j;
            const float xc = x[b * N_SZ + n];
            const f32x4 yc = *(const f32x4*)(y + ((size_t)b * N_SZ + n) * C_SZ + cg * 4);
            const float d0 = xc - tv0, d1 = xc - tv1;
            const float q0 = d0 * d0,  q1 = d1 * d1;
#pragma unroll
            for (int cc = 0; cc < 4; ++cc) {
                acc0[cc] = fmaf(__builtin_amdgcn_exp2f(q0 * kl[cc]), yc[cc], acc0[cc]);
                acc1[cc] = fmaf(__builtin_amdgcn_exp2f(q1 * kl[cc]), yc[cc], acc1[cc]);
            }
        }
#pragma unroll
        for (int mask = 4; mask <= 32; mask <<= 1) {
#pragma unroll
            for (int cc = 0; cc < 4; ++cc) {
                acc0[cc] += __shfl_xor(acc0[cc], mask);
                acc1[cc] += __shfl_xor(acc1[cc], mask);
            }
        }
        float* rp = &red[0][0][0]; // reuse as [16 m][16 c]
        if (lane < 4) {
            *(f32x4*)(rp + (w * 2 + 0) * 16 + lane * 4) = acc0;
            *(f32x4*)(rp + (w * 2 + 1) * 16 + lane * 4) = acc1;
        }
        __syncthreads();
        {
            const int mi = tid >> 5, o = tid & 31;
            const float* wr = W + o * C_SZ;
            float v = bias[o];
#pragma unroll
            for (int cc = 0; cc < C_SZ; ++cc) v = fmaf(rp[mi * 16 + cc], wr[cc], v);
            out[((size_t)(b * M_SZ + mg * 16 + mi)) * O_SZ + o] = v;
        }
    }
}

extern "C" void kernel_launch(void* const* d_in, const int* in_sizes, int n_in,
                              void* d_out, int out_size, void* d_ws, size_t ws_size,
                              hipStream_t stream) {
    const float* x     = (const float*)d_in[0];
    const float* y     = (const float*)d_in[1];
    const float* t     = (const float*)d_in[2];
    const float* sigma = (const float*)d_in[3];
    const float* W     = (const float*)d_in[4];
    const float* bias  = (const float*)d_in[5];
    float* out = (float*)d_out;

    setconv_fused<<<B_SZ * 64, 512, 0, stream>>>(x, y, t, sigma, W, bias, out);
}

// Round 9
// 9.688 us; speedup vs baseline: 1.0473x; 1.0473x over previous
//
#include <hip/hip_runtime.h>

// SetConv, single fused kernel (uniform-sigma MFMA fast path).
//
//   G[b,m,c] = sum_n exp2(kcu*(x[b,n]-t[b,m])^2) * y[b,n,c]
//   out[b,m,o] = sum_c G[b,m,c]*W[o,c] + bias[o],  kcu = -0.5*log2e/exp(sigma)^2
//
// L2-BW analysis (R8): every block streams all of y[b] (512 KB); 512 blocks
// = 264 MB of L2 traffic ~ 7.7 us at 34.5 TB/s -- matched measured 9.6-10.1.
// This round: 32-m tile per block -> 256 blocks -> 132 MB L2 (~3.8 us), and
// XCD swizzle (b = blockIdx&7) so each XCD touches only one b's y panel
// (512 KB unique -> single HBM fetch, L2-resident thereafter).
//
// Grid: 256 blocks x 512 threads (8 waves). Block = (b, 32-m tile); waves
// split n 8-way (128 n/wave = 4 chunks of 32). Per chunk: one shared y
// B-fragment, two A-fragments (m-subtiles 0:16, 16:32) generated as
// u=fma(su,x,nst), e=exp2(-u*u), packed via v_cvt_pkrtz; two MFMAs.
// No pre-loop barrier: all global loads issued at entry, waves independent
// until the 8-way LDS reduce.
//
// non-uniform sigma: correct VALU fallback (never taken for this input).
//
// Fragment layouts (gfx950 16x16x32, verified round 3, absmax 0.125):
//   A: lane l -> row m = l&15, k = 4*(l>>4) + (j&3) + 16*(j>>2), j=0..7
//   B: lane l -> col c = l&15, k same mapping
//   D: lane l -> col c = l&15, row m = 4*(l>>4) + reg

#define B_SZ 8
#define N_SZ 1024
#define M_SZ 1024
#define C_SZ 16
#define O_SZ 32
#define LOG2E 1.4426950408889634f

typedef _Float16 f16x8 __attribute__((ext_vector_type(8)));
typedef __fp16   h16x2 __attribute__((ext_vector_type(2)));  // cvt_pkrtz return type
typedef float    f32x4 __attribute__((ext_vector_type(4)));

__global__ __launch_bounds__(512, 2) void setconv_fused(
    const float* __restrict__ x,     // (B, N)
    const float* __restrict__ y,     // (B, N, C)
    const float* __restrict__ t,     // (B, M)
    const float* __restrict__ sigma, // (C)
    const float* __restrict__ W,     // (O, C)
    const float* __restrict__ bias,  // (O)
    float* __restrict__ out)         // (B, M, O)
{
    const int tid  = threadIdx.x;
    const int w    = tid >> 6;   // wave 0..7 = n-eighth
    const int lane = tid & 63;
    // XCD-affinity: round-robin block->XCD means blockIdx&7 selects the XCD;
    // give each XCD a single b so its y panel (512 KB) is L2-resident.
    const int b  = blockIdx.x & 7;
    const int mg = blockIdx.x >> 3;   // 0..31, m0 = mg*32

    const int g  = lane >> 4;
    const int g4 = 4 * g;
    const int c  = lane & 15;

    __shared__ float red[8][32][16];    // 16 KB: [wave][m][c]

    // ================= hoisted, unconditional global loads =================
    // (1) y B-fragments in fragment order: lane l -> col c, rows per quarter
    const float* ybc = y + ((size_t)b * N_SZ + w * 128) * C_SZ + c;
    float yraw[32];
#pragma unroll
    for (int kc = 0; kc < 4; ++kc) {
#pragma unroll
        for (int jj = 0; jj < 4; ++jj) {
            yraw[kc * 8 + jj]     = ybc[(kc * 32 + g4 + jj) * C_SZ];
            yraw[kc * 8 + 4 + jj] = ybc[(kc * 32 + 16 + g4 + jj) * C_SZ];
        }
    }
    // (2) x slices for this lane's k positions (broadcast across the 16
    //     lanes sharing g; dwordx4 each)
    const float* xw = x + b * N_SZ + w * 128;
    f32x4 xlo[4], xhi[4];
#pragma unroll
    for (int kc = 0; kc < 4; ++kc) {
        xlo[kc] = *(const f32x4*)(xw + kc * 32 + g4);
        xhi[kc] = *(const f32x4*)(xw + kc * 32 + 16 + g4);
    }
    // (3) t values for this lane's two m-columns
    const float tm0 = t[b * M_SZ + mg * 32 + c];
    const float tm1 = t[b * M_SZ + mg * 32 + 16 + c];
    // (4) sigma
    f32x4 s0 = *(const f32x4*)(sigma + 0);
    f32x4 s1 = *(const f32x4*)(sigma + 4);
    f32x4 s2 = *(const f32x4*)(sigma + 8);
    f32x4 s3 = *(const f32x4*)(sigma + 12);

    // work in the load shadow: uni check + y f16 conversion
    const bool uni =
        (s0[0]==s0[1]) && (s0[0]==s0[2]) && (s0[0]==s0[3]) &&
        (s0[0]==s1[0]) && (s0[0]==s1[1]) && (s0[0]==s1[2]) && (s0[0]==s1[3]) &&
        (s0[0]==s2[0]) && (s0[0]==s2[1]) && (s0[0]==s2[2]) && (s0[0]==s2[3]) &&
        (s0[0]==s3[0]) && (s0[0]==s3[1]) && (s0[0]==s3[2]) && (s0[0]==s3[3]);

    f16x8 bf[4];
#pragma unroll
    for (int kc = 0; kc < 4; ++kc)
#pragma unroll
        for (int j = 0; j < 8; ++j)
            bf[kc][j] = (_Float16)yraw[kc * 8 + j];

    if (uni) {
        const float kcu  = -0.5f * LOG2E * __builtin_amdgcn_exp2f(-2.0f * LOG2E * s0[0]);
        const float su   = __builtin_sqrtf(-kcu);   // kcu < 0
        const float nst0 = -su * tm0;
        const float nst1 = -su * tm1;

        f32x4 acc0 = {0.f, 0.f, 0.f, 0.f};   // m-subtile 0 (rows mg*32 + 0:16)
        f32x4 acc1 = {0.f, 0.f, 0.f, 0.f};   // m-subtile 1 (rows mg*32 + 16:32)

#pragma unroll
        for (int kc = 0; kc < 4; ++kc) {
            float e0[8], e1[8];
#pragma unroll
            for (int j = 0; j < 4; ++j) {
                const float u0 = fmaf(su, xlo[kc][j], nst0);
                const float v0 = fmaf(su, xhi[kc][j], nst0);
                const float u1 = fmaf(su, xlo[kc][j], nst1);
                const float v1 = fmaf(su, xhi[kc][j], nst1);
                e0[j]     = __builtin_amdgcn_exp2f(-u0 * u0);
                e0[4 + j] = __builtin_amdgcn_exp2f(-v0 * v0);
                e1[j]     = __builtin_amdgcn_exp2f(-u1 * u1);
                e1[4 + j] = __builtin_amdgcn_exp2f(-v1 * v1);
            }
            union { h16x2 p2[4]; f16x8 v8; } a0, a1;
#pragma unroll
            for (int p = 0; p < 4; ++p) {
                a0.p2[p] = __builtin_amdgcn_cvt_pkrtz(e0[2 * p], e0[2 * p + 1]);
                a1.p2[p] = __builtin_amdgcn_cvt_pkrtz(e1[2 * p], e1[2 * p + 1]);
            }
            acc0 = __builtin_amdgcn_mfma_f32_16x16x32_f16(a0.v8, bf[kc], acc0, 0, 0, 0);
            acc1 = __builtin_amdgcn_mfma_f32_16x16x32_f16(a1.v8, bf[kc], acc1, 0, 0, 0);
        }

        // D: lane -> col c = lane&15, row m = g*4 + r
#pragma unroll
        for (int r = 0; r < 4; ++r) {
            red[w][g * 4 + r][c]      = acc0[r];
            red[w][16 + g * 4 + r][c] = acc1[r];
        }
        __syncthreads();

        // step 1: reduce over waves (512 threads: one (mi, cc) each)
        {
            const int mi = tid >> 4, cc = tid & 15;
            float s = red[0][mi][cc];
#pragma unroll
            for (int wv = 1; wv < 8; ++wv) s += red[wv][mi][cc];
            red[0][mi][cc] = s;   // own slot, no cross-thread hazard
        }
        __syncthreads();

        // step 2: 16->32 linear, 1024 outputs / 512 threads = 2 each
#pragma unroll
        for (int u = 0; u < 2; ++u) {
            const int idx = tid + u * 512;
            const int mi = idx >> 5, o = idx & 31;
            const float* gr = &red[0][mi][0];
            const float* wr = W + o * C_SZ;
            float v = bias[o];
#pragma unroll
            for (int cc = 0; cc < C_SZ; ++cc) v = fmaf(gr[cc], wr[cc], v);
            out[((size_t)(b * M_SZ + mg * 32 + mi)) * O_SZ + o] = v;
        }
    } else {
        // -------- fallback: arbitrary per-channel sigma (VALU path) --------
        const int j  = lane >> 2;  // 16 n per iter
        const int cg = lane & 3;   // 4 channels
        f32x4 slv = *(const f32x4*)(sigma + cg * 4);
        f32x4 kl;
#pragma unroll
        for (int cc = 0; cc < 4; ++cc)
            kl[cc] = -0.5f * LOG2E * __builtin_amdgcn_exp2f(-2.0f * LOG2E * slv[cc]);

        // wave w owns m = mg*32 + w*4 + {0..3}
        float tv[4];
#pragma unroll
        for (int mm = 0; mm < 4; ++mm)
            tv[mm] = t[b * M_SZ + mg * 32 + w * 4 + mm];

        f32x4 acc[4];
#pragma unroll
        for (int mm = 0; mm < 4; ++mm) acc[mm] = (f32x4){0.f, 0.f, 0.f, 0.f};

        for (int it = 0; it < 64; ++it) {
            const int n = it * 16 + j;
            const float xc = x[b * N_SZ + n];
            const f32x4 yc = *(const f32x4*)(y + ((size_t)b * N_SZ + n) * C_SZ + cg * 4);
#pragma unroll
            for (int mm = 0; mm < 4; ++mm) {
                const float d = xc - tv[mm];
                const float q = d * d;
#pragma unroll
                for (int cc = 0; cc < 4; ++cc)
                    acc[mm][cc] = fmaf(__builtin_amdgcn_exp2f(q * kl[cc]), yc[cc], acc[mm][cc]);
            }
        }
#pragma unroll
        for (int mm = 0; mm < 4; ++mm)
#pragma unroll
            for (int mask = 4; mask <= 32; mask <<= 1)
#pragma unroll
                for (int cc = 0; cc < 4; ++cc)
                    acc[mm][cc] += __shfl_xor(acc[mm][cc], mask);

        float* rp = &red[0][0][0]; // reuse as [32 m][16 c]
        if (lane < 4) {
#pragma unroll
            for (int mm = 0; mm < 4; ++mm)
                *(f32x4*)(rp + (w * 4 + mm) * 16 + lane * 4) = acc[mm];
        }
        __syncthreads();
#pragma unroll
        for (int u = 0; u < 2; ++u) {
            const int idx = tid + u * 512;
            const int mi = idx >> 5, o = idx & 31;
            const float* wr = W + o * C_SZ;
            float v = bias[o];
#pragma unroll
            for (int cc = 0; cc < C_SZ; ++cc) v = fmaf(rp[mi * 16 + cc], wr[cc], v);
            out[((size_t)(b * M_SZ + mg * 32 + mi)) * O_SZ + o] = v;
        }
    }
}

extern "C" void kernel_launch(void* const* d_in, const int* in_sizes, int n_in,
                              void* d_out, int out_size, void* d_ws, size_t ws_size,
                              hipStream_t stream) {
    const float* x     = (const float*)d_in[0];
    const float* y     = (const float*)d_in[1];
    const float* t     = (const float*)d_in[2];
    const float* sigma = (const float*)d_in[3];
    const float* W     = (const float*)d_in[4];
    const float* bias  = (const float*)d_in[5];
    float* out = (float*)d_out;

    // 256 blocks: (mg 0..31) x (b 0..7 in the low bits for XCD affinity)
    setconv_fused<<<256, 512, 0, stream>>>(x, y, t, sigma, W, bias, out);
}